// Round 21
// baseline (243.146 us; speedup 1.0000x reference)
//
#include <hip/hip_runtime.h>
#include <math.h>

// Problem constants (B=8, N=2048, D=256, H=8, Dh=32)
#define BATCH 8
#define SEQ   2048
#define DIM   256
#define NHEAD 8
#define DHEAD 32
#define MROWS (BATCH*SEQ)   // 16384
#define KCAT  768           // concatenated qkv/pos K-dim
#define SZE   ((size_t)MROWS * DIM)   // 4,194,304 elements

typedef short bf16x8 __attribute__((ext_vector_type(8)));
typedef float f32x4  __attribute__((ext_vector_type(4)));

#define CLSCALE 0.25503485f   // log2(e)/sqrt(32): Q pre-scaled by this in mgemm

// raw hardware exp2 (single v_exp_f32; inputs are bounded log2-units,
// masked scores are -3e38 -> exp2 -> 0; no range reduction needed)
static __device__ __forceinline__ float exp2_raw(float x) {
    float r;
    asm("v_exp_f32 %0, %1" : "=v"(r) : "v"(x));
    return r;
}

// fp32 -> bf16 round-to-nearest-even (bits)
static __device__ __forceinline__ unsigned bf16rne(float f) {
    unsigned u = __float_as_uint(f);
    return (u + 0x7FFFu + ((u >> 16) & 1u)) >> 16;
}

// ---------------------------------------------------------------------------
// Fused fp32 -> bf16 convert of x and pos into concatenated acat[M,768]:
// row r = [ x[r,0:256] | pos[r,0:512] ]  (bf16). 8 elems/thread.
// ---------------------------------------------------------------------------
__global__ __launch_bounds__(256) void convcat_kernel(
    const float* __restrict__ x, const float* __restrict__ pos,
    unsigned short* __restrict__ acat, int n1, int n2)
{
    int i = blockIdx.x * 256 + threadIdx.x;
    const float* s; size_t dst; int j;
    if (i < n1) {                      // x chunk: 32 chunks/row of 256 cols
        j = i; s = x;
        int row = j >> 5, c8 = (j & 31) * 8;
        dst = (size_t)row * KCAT + c8;
    } else {                           // pos chunk: 64 chunks/row of 512 cols
        j = i - n1; if (j >= n2) return; s = pos;
        int row = j >> 6, c8 = (j & 63) * 8;
        dst = (size_t)row * KCAT + 256 + c8;
    }
    float4 a = ((const float4*)s)[2 * j];
    float4 b = ((const float4*)s)[2 * j + 1];
    union { unsigned short u[8]; uint4 v; } o;
    o.u[0] = bf16rne(a.x); o.u[1] = bf16rne(a.y);
    o.u[2] = bf16rne(a.z); o.u[3] = bf16rne(a.w);
    o.u[4] = bf16rne(b.x); o.u[5] = bf16rne(b.y);
    o.u[6] = bf16rne(b.z); o.u[7] = bf16rne(b.w);
    *(uint4*)&acat[dst] = o.v;
}

// ---------------------------------------------------------------------------
// All 5 weight transposes in ONE launch (960 blocks, blockIdx-range dispatch).
// ---------------------------------------------------------------------------
__global__ __launch_bounds__(256) void wtrans_all_kernel(
    const float* __restrict__ Wqkv, const float* __restrict__ Wpos,
    const float* __restrict__ W1, const float* __restrict__ W2,
    unsigned short* __restrict__ wqk, unsigned short* __restrict__ wv,
    unsigned short* __restrict__ w1, unsigned short* __restrict__ w2)
{
    int b = blockIdx.x;
    const float* src; unsigned short* dst;
    int srcN, srcColOff, dstK, dstKOff, nbx;
    if (b < 128)      {          src = Wqkv; dst = wqk; srcN = 768;  srcColOff = 0;   dstK = 768;  dstKOff = 0;   nbx = 16; }
    else if (b < 384) { b -= 128; src = Wpos; dst = wqk; srcN = 512;  srcColOff = 0;   dstK = 768;  dstKOff = 256; nbx = 16; }
    else if (b < 448) { b -= 384; src = Wqkv; dst = wv;  srcN = 768;  srcColOff = 512; dstK = 256;  dstKOff = 0;   nbx = 8;  }
    else if (b < 704) { b -= 448; src = W1;   dst = w1;  srcN = 1024; srcColOff = 0;   dstK = 256;  dstKOff = 0;   nbx = 32; }
    else              { b -= 704; src = W2;   dst = w2;  srcN = 256;  srcColOff = 0;   dstK = 1024; dstKOff = 0;   nbx = 8;  }
    const int tn0 = (b % nbx) * 32;
    const int tk0 = (b / nbx) * 32;

    __shared__ float tile[32][33];
    const int tx = threadIdx.x & 31;
    const int ty = threadIdx.x >> 5;
    #pragma unroll
    for (int r = ty; r < 32; r += 8)
        tile[r][tx] = src[(size_t)(tk0 + r) * srcN + srcColOff + tn0 + tx];
    __syncthreads();
    #pragma unroll
    for (int r = ty; r < 32; r += 8)
        dst[(size_t)(tn0 + r) * dstK + dstKOff + tk0 + tx] =
            (unsigned short)bf16rne(tile[tx][r]);
}

// ---------------------------------------------------------------------------
// bf16 MFMA GEMM body (device fn): C[M,Nc] = A[M,K] @ Wt[Nc,K]^T + bias.
// 128x128 tile at (bx,by), 4 waves 2x2, 4x4 frags of 16x16x32, operands
// direct from global with register double-buffer prefetch (K mult of 64).
// Epilogue modes:
//   0: fp32 store   1: relu->bf16 store
//   4: qk scatter (col<256: q = (acc+bias+bias2)*CLSCALE ->bf16 u0;
//                  else    : k = acc+bias+bias2 ->bf16 u1), [B,H,N,Dh] layout
//   5: v -> vt[b,h,d,n] TRANSPOSED (4 regs = 4 consecutive n, one 8B store)
// ---------------------------------------------------------------------------
template<int MODE>
static __device__ __forceinline__ void mgemm_body(
    int bx, int by,
    const unsigned short* __restrict__ A, const unsigned short* __restrict__ Wt,
    const float* __restrict__ bias, const float* __restrict__ bias2,
    float* __restrict__ C, unsigned short* __restrict__ Cb,
    int M, int K, int Nc, int lda,
    unsigned short* __restrict__ u0, unsigned short* __restrict__ u1,
    unsigned short* __restrict__ u2)
{
    const int t    = threadIdx.x;
    const int wv   = t >> 6;
    const int lane = t & 63;
    const int g    = lane >> 4;
    const int lo   = lane & 15;
    const int wr   = wv >> 1;
    const int wc   = wv & 1;
    const int r0   = by * 128 + wr * 64;
    const int c0   = bx * 128 + wc * 64;

    f32x4 acc[4][4];
    #pragma unroll
    for (int i = 0; i < 4; ++i)
        #pragma unroll
        for (int j = 0; j < 4; ++j)
            #pragma unroll
            for (int r = 0; r < 4; ++r) acc[i][j][r] = 0.f;

    const unsigned short* aP[4];
    const unsigned short* bP[4];
    #pragma unroll
    for (int i = 0; i < 4; ++i) {
        aP[i] = A  + (size_t)(r0 + 16 * i + lo) * lda + g * 8;
        bP[i] = Wt + (size_t)(c0 + 16 * i + lo) * K + g * 8;
    }

    bf16x8 aA[4], bA[4], aB[4], bB[4];
    #pragma unroll
    for (int i = 0; i < 4; ++i) {
        aA[i] = *(const bf16x8*)(aP[i]);
        bA[i] = *(const bf16x8*)(bP[i]);
    }

    for (int k0 = 0; k0 < K; k0 += 64) {
        #pragma unroll
        for (int i = 0; i < 4; ++i) {
            aB[i] = *(const bf16x8*)(aP[i] + k0 + 32);
            bB[i] = *(const bf16x8*)(bP[i] + k0 + 32);
        }
        #pragma unroll
        for (int i = 0; i < 4; ++i)
            #pragma unroll
            for (int j = 0; j < 4; ++j)
                acc[i][j] = __builtin_amdgcn_mfma_f32_16x16x32_bf16(
                    aA[i], bA[j], acc[i][j], 0, 0, 0);
        if (k0 + 64 < K) {
            #pragma unroll
            for (int i = 0; i < 4; ++i) {
                aA[i] = *(const bf16x8*)(aP[i] + k0 + 64);
                bA[i] = *(const bf16x8*)(bP[i] + k0 + 64);
            }
        }
        #pragma unroll
        for (int i = 0; i < 4; ++i)
            #pragma unroll
            for (int j = 0; j < 4; ++j)
                acc[i][j] = __builtin_amdgcn_mfma_f32_16x16x32_bf16(
                    aB[i], bB[j], acc[i][j], 0, 0, 0);
    }

    #pragma unroll
    for (int j = 0; j < 4; ++j) {
        const int col = c0 + 16 * j + lo;
        const float bs = bias[col] + ((MODE == 4) ? bias2[col] : 0.f);
        #pragma unroll
        for (int i = 0; i < 4; ++i) {
            if (MODE == 5) {
                // transposed v write: 4 regs = 4 consecutive n at one (h,d)
                const int row0 = r0 + 16 * i + g * 4;   // 4-aligned, block
                const int bb   = row0 >> 11;            //   never crosses batch
                const int nn0  = row0 & (SEQ - 1);
                const int hh   = col >> 5;
                const int dh   = col & 31;
                uint2 pk;
                pk.x = bf16rne(acc[i][j][0] + bs) | (bf16rne(acc[i][j][1] + bs) << 16);
                pk.y = bf16rne(acc[i][j][2] + bs) | (bf16rne(acc[i][j][3] + bs) << 16);
                *(uint2*)&u2[(((size_t)bb * NHEAD + hh) * DHEAD + dh) * SEQ + nn0] = pk;
            } else {
                #pragma unroll
                for (int r = 0; r < 4; ++r) {
                    const int row = r0 + 16 * i + g * 4 + r;
                    float v = acc[i][j][r] + bs;
                    if (MODE == 0) {
                        C[(size_t)row * Nc + col] = v;
                    } else if (MODE == 1) {
                        Cb[(size_t)row * Nc + col] =
                            (unsigned short)bf16rne(fmaxf(v, 0.f));
                    } else {   // MODE 4
                        const int bb = row >> 11;
                        const int nn = row & (SEQ - 1);
                        const int which = col >> 8;        // 0:q 1:k
                        const int d  = col & 255;
                        const int hh = d >> 5;
                        const int dh = d & 31;
                        const size_t dst =
                            (((size_t)bb * NHEAD + hh) * SEQ + nn) * DHEAD + dh;
                        if (which == 0) {
                            u0[dst] = (unsigned short)bf16rne(v * CLSCALE);
                        } else {
                            u1[dst] = (unsigned short)bf16rne(v);
                        }
                    }
                }
            }
        }
    }
}

// standalone template kernel (FFN1 = MODE 1, FFN2 = MODE 0)
template<int MODE>
__global__ __launch_bounds__(256, 3) void mgemm_kernel(
    const unsigned short* __restrict__ A, const unsigned short* __restrict__ Wt,
    const float* __restrict__ bias, const float* __restrict__ bias2,
    float* __restrict__ C, unsigned short* __restrict__ Cb,
    int M, int K, int Nc, int lda,
    unsigned short* __restrict__ u0, unsigned short* __restrict__ u1,
    unsigned short* __restrict__ u2)
{
    mgemm_body<MODE>(blockIdx.x, blockIdx.y, A, Wt, bias, bias2, C, Cb,
                     M, K, Nc, lda, u0, u1, u2);
}

// merged qkv kernel: blocks [0,512) = qk GEMM (MODE 4, grid 4x128);
//                    blocks [512,768) = v GEMM (MODE 5, grid 2x128).
__global__ __launch_bounds__(256, 3) void qkv_kernel(
    const unsigned short* __restrict__ acat,
    const unsigned short* __restrict__ wqk, const unsigned short* __restrict__ wv,
    const float* __restrict__ bqkv, const float* __restrict__ bpos,
    unsigned short* __restrict__ qb, unsigned short* __restrict__ kb,
    unsigned short* __restrict__ vt)
{
    const int b = blockIdx.x;
    if (b < 512) {
        mgemm_body<4>(b & 3, b >> 2, acat, wqk, bqkv, bpos, nullptr, nullptr,
                      MROWS, KCAT, 512, KCAT, qb, kb, nullptr);
    } else {
        const int b2 = b - 512;
        mgemm_body<5>(b2 & 1, b2 >> 1, acat, wv, bqkv + 512, nullptr,
                      nullptr, nullptr, MROWS, 256, 256, KCAT,
                      nullptr, nullptr, vt);
    }
}

// ---------------------------------------------------------------------------
// MFMA flash attention, SPLIT-K over keys: grid 1024 = 64 bh x 8 qblk x 2 kh.
// Each block processes keys [kh*1024, kh*1024+1024) for its 256 q rows and
// writes UN-NORMALIZED fp32 partials accP[kh] (O-layout) + row sums lP[kh].
// Valid because static-max softmax (p = exp2(s), no running max) makes
// partials additive: O = (A0+A1)/(l0+l1); combine is folded into LN1.
// Inner loop byte-identical to the proven round-16 kernel.
// XCD swizzle keeps each bh's 16 blocks on one XCD (K+V 2MB < 4MB L2).
// ---------------------------------------------------------------------------
__global__ __launch_bounds__(256) void attn_kernel(
    const unsigned short* __restrict__ Qb, const unsigned short* __restrict__ Kb,
    const unsigned short* __restrict__ Vt, const int* __restrict__ mask,
    float* __restrict__ accP, float* __restrict__ lP)
{
    __shared__ float bias_s[SEQ];        // 8 KB mask bias (0 / -3e38)
    __shared__ float T[4][32][17];       // per-wave O^T transpose staging

    const int t    = threadIdx.x;
    const int wv   = t >> 6;
    const int lane = t & 63;
    const int g    = lane >> 4;
    const int lo   = lane & 15;

    const int sb   = ((blockIdx.x & 7) << 7) | (blockIdx.x >> 3);  // XCD swizzle
    const int bh   = sb >> 4;            // 0..63
    const int qblk = (sb >> 1) & 7;      // 0..7
    const int kh   = sb & 1;             // key half
    const int bb   = bh >> 3;
    const int hh   = bh & 7;
    const int qt   = qblk * 256 + wv * 64;   // wave owns q rows qt..qt+63
    const int khoff = kh * (SEQ / 2);

    const int* mrow = mask + bb * SEQ;
    for (int i = t; i < SEQ; i += 256)
        bias_s[i] = mrow[i] ? -3.0e38f : 0.0f;
    __syncthreads();

    const unsigned short* Qh = Qb + (size_t)bh * SEQ * 32;
    const unsigned short* Kh = Kb + (size_t)bh * SEQ * 32;
    const unsigned short* Vh = Vt + (size_t)bh * 32 * SEQ;

    bf16x8 qf[4];
    #pragma unroll
    for (int i = 0; i < 4; ++i)
        qf[i] = *(const bf16x8*)&Qh[(size_t)(qt + 16 * i + lo) * 32 + g * 8];

    f32x4 acc[4][2];                     // [q-tile][d-half]
    #pragma unroll
    for (int i = 0; i < 4; ++i)
        #pragma unroll
        for (int hf = 0; hf < 2; ++hf)
            #pragma unroll
            for (int r = 0; r < 4; ++r) acc[i][hf][r] = 0.f;
    float l[4] = {0.f, 0.f, 0.f, 0.f};

    // bpermute byte addresses (hoisted): source lanes 32*(g&1)+lo and +16
    const int a0 = ((((g & 1) << 5) + lo) << 2);
    const int a1 = a0 + 64;

    for (int k0 = khoff; k0 < khoff + SEQ / 2; k0 += 64) {
        bf16x8 kf[4], vf[4];
        #pragma unroll
        for (int c = 0; c < 4; ++c)
            kf[c] = *(const bf16x8*)&Kh[(size_t)(k0 + c * 16 + lo) * 32 + g * 8];
        vf[0] = *(const bf16x8*)&Vh[(size_t)lo * SEQ + k0 + g * 8];
        vf[1] = *(const bf16x8*)&Vh[(size_t)(16 + lo) * SEQ + k0 + g * 8];
        vf[2] = *(const bf16x8*)&Vh[(size_t)lo * SEQ + k0 + 32 + g * 8];
        vf[3] = *(const bf16x8*)&Vh[(size_t)(16 + lo) * SEQ + k0 + 32 + g * 8];

        f32x4 cb[4];
        #pragma unroll
        for (int c = 0; c < 4; ++c)
            cb[c] = *(const f32x4*)&bias_s[k0 + c * 16 + 4 * g];

        #pragma unroll
        for (int i = 0; i < 4; ++i) {
            // ---- QK^T: 4 independent MFMAs, 64 keys ----
            f32x4 s[4];
            __builtin_amdgcn_s_setprio(1);
            #pragma unroll
            for (int c = 0; c < 4; ++c)
                s[c] = __builtin_amdgcn_mfma_f32_16x16x32_bf16(
                    kf[c], qf[i], cb[c], 0, 0, 0);
            __builtin_amdgcn_s_setprio(0);

            // ---- p = exp2(s) via raw v_exp_f32, pack to bf16 ----
            unsigned wA[4], wB[4];
            float tl = 0.f;
            #pragma unroll
            for (int c = 0; c < 4; ++c) {
                float p0 = exp2_raw(s[c][0]);
                float p1 = exp2_raw(s[c][1]);
                float p2 = exp2_raw(s[c][2]);
                float p3 = exp2_raw(s[c][3]);
                tl += (p0 + p1) + (p2 + p3);
                asm("v_cvt_pk_bf16_f32 %0, %1, %2"
                    : "=v"(wA[c]) : "v"(p0), "v"(p1));
                asm("v_cvt_pk_bf16_f32 %0, %1, %2"
                    : "=v"(wB[c]) : "v"(p2), "v"(p3));
            }
            l[i] += tl;   // per-lane partial; cross-lane sum in epilogue

            // ---- PV per 32-key chunk ----
            #pragma unroll
            for (int kc = 0; kc < 2; ++kc) {
                const int c0 = 2 * kc, c1 = 2 * kc + 1;
                int x0 = __builtin_amdgcn_ds_bpermute(a0, (int)wA[c0]);
                int y0 = __builtin_amdgcn_ds_bpermute(a0, (int)wA[c1]);
                int x1 = __builtin_amdgcn_ds_bpermute(a0, (int)wB[c0]);
                int y1 = __builtin_amdgcn_ds_bpermute(a0, (int)wB[c1]);
                int x2 = __builtin_amdgcn_ds_bpermute(a1, (int)wA[c0]);
                int y2 = __builtin_amdgcn_ds_bpermute(a1, (int)wA[c1]);
                int x3 = __builtin_amdgcn_ds_bpermute(a1, (int)wB[c0]);
                int y3 = __builtin_amdgcn_ds_bpermute(a1, (int)wB[c1]);
                const bool hi2 = g >= 2;
                union { int u[4]; bf16x8 v; } pf;
                pf.u[0] = hi2 ? y0 : x0;
                pf.u[1] = hi2 ? y1 : x1;
                pf.u[2] = hi2 ? y2 : x2;
                pf.u[3] = hi2 ? y3 : x3;

                __builtin_amdgcn_s_setprio(1);
                acc[i][0] = __builtin_amdgcn_mfma_f32_16x16x32_bf16(
                    vf[2 * kc + 0], pf.v, acc[i][0], 0, 0, 0);
                acc[i][1] = __builtin_amdgcn_mfma_f32_16x16x32_bf16(
                    vf[2 * kc + 1], pf.v, acc[i][1], 0, 0, 0);
                __builtin_amdgcn_s_setprio(0);
            }
        }
    }

    // epilogue: finish l, store UN-NORMALIZED partials + l (no divide)
    float* accH = accP + (size_t)kh * SZE;
    #pragma unroll
    for (int i = 0; i < 4; ++i) {
        l[i] += __shfl_xor(l[i], 16);
        l[i] += __shfl_xor(l[i], 32);
        if (lane < 16)
            lP[(size_t)kh * 64 * SEQ + (size_t)bh * SEQ + qt + 16 * i + lane] = l[i];
        #pragma unroll
        for (int hf = 0; hf < 2; ++hf)
            #pragma unroll
            for (int r = 0; r < 4; ++r)
                T[wv][hf * 16 + g * 4 + r][lo] = acc[i][hf][r];
        __syncthreads();
        #pragma unroll
        for (int p = 0; p < 2; ++p) {
            int row = p * 8 + (lane >> 3);
            int d4  = (lane & 7) * 4;
            float4 ov;
            ov.x = T[wv][d4 + 0][row];
            ov.y = T[wv][d4 + 1][row];
            ov.z = T[wv][d4 + 2][row];
            ov.w = T[wv][d4 + 3][row];
            *(float4*)&accH[(size_t)(bb * SEQ + qt + i * 16 + row) * DIM + hh * 32 + d4] = ov;
        }
        __syncthreads();
    }
}

// ---------------------------------------------------------------------------
// LN1 + split-K combine: h = LN(x + (A0+A1)/(l0+l1)). 1 wave = 1 row.
// h index for this lane's 4 cols: h = lane>>3 (cols 4*lane..4*lane+3).
// Outputs fp32 hbuf + bf16 hb.
// ---------------------------------------------------------------------------
__global__ __launch_bounds__(256) void ln1c_kernel(
    const float* __restrict__ X, const float* __restrict__ accP,
    const float* __restrict__ lP,
    const float* __restrict__ gam, const float* __restrict__ bet,
    float* __restrict__ Y, unsigned short* __restrict__ Yb)
{
    const int lane = threadIdx.x & 63;
    const int row  = blockIdx.x * 4 + (threadIdx.x >> 6);
    const size_t off = (size_t)row * DIM + lane * 4;

    const int h   = lane >> 3;
    const int bbv = row >> 11;
    const int nn  = row & (SEQ - 1);
    const size_t bhn = ((size_t)bbv * NHEAD + h) * SEQ + nn;
    const float ls = lP[bhn] + lP[(size_t)64 * SEQ + bhn];
    const float inv = (ls > 0.f) ? 1.0f / ls : 0.f;

    float4 xv = *(const float4*)&X[off];
    float4 a0 = *(const float4*)&accP[off];
    float4 a1 = *(const float4*)&accP[SZE + off];
    float4 v;
    v.x = xv.x + (a0.x + a1.x) * inv;
    v.y = xv.y + (a0.y + a1.y) * inv;
    v.z = xv.z + (a0.z + a1.z) * inv;
    v.w = xv.w + (a0.w + a1.w) * inv;

    float s = (v.x + v.y) + (v.z + v.w);
    #pragma unroll
    for (int o = 1; o < 64; o <<= 1) s += __shfl_xor(s, o);
    const float mu = s * (1.f / 256.f);

    float4 d;
    d.x = v.x - mu; d.y = v.y - mu; d.z = v.z - mu; d.w = v.w - mu;
    float s2 = (d.x * d.x + d.y * d.y) + (d.z * d.z + d.w * d.w);
    #pragma unroll
    for (int o = 1; o < 64; o <<= 1) s2 += __shfl_xor(s2, o);
    const float rs = rsqrtf(s2 * (1.f / 256.f) + 1e-5f);

    float4 gv = *(const float4*)&gam[lane * 4];
    float4 bv = *(const float4*)&bet[lane * 4];
    float4 y;
    y.x = d.x * rs * gv.x + bv.x;
    y.y = d.y * rs * gv.y + bv.y;
    y.z = d.z * rs * gv.z + bv.z;
    y.w = d.w * rs * gv.w + bv.w;
    *(float4*)&Y[off] = y;

    uint2 pk;
    pk.x = bf16rne(y.x) | (bf16rne(y.y) << 16);
    pk.y = bf16rne(y.z) | (bf16rne(y.w) << 16);
    *(uint2*)&Yb[off] = pk;
}

// ---------------------------------------------------------------------------
// Fused residual + LayerNorm (LN2, in-place capable): 1 wave = 1 row.
// ---------------------------------------------------------------------------
__global__ __launch_bounds__(256) void ln_kernel(
    const float* __restrict__ X, const float* __restrict__ R,
    const float* __restrict__ gam, const float* __restrict__ bet,
    float* __restrict__ Y)
{
    const int lane = threadIdx.x & 63;
    const int row  = blockIdx.x * 4 + (threadIdx.x >> 6);
    const size_t off = (size_t)row * DIM + lane * 4;

    float4 xv = *(const float4*)&X[off];
    float4 rv = *(const float4*)&R[off];
    float4 v;
    v.x = xv.x + rv.x; v.y = xv.y + rv.y;
    v.z = xv.z + rv.z; v.w = xv.w + rv.w;

    float s = (v.x + v.y) + (v.z + v.w);
    #pragma unroll
    for (int o = 1; o < 64; o <<= 1) s += __shfl_xor(s, o);
    const float mu = s * (1.f / 256.f);

    float4 d;
    d.x = v.x - mu; d.y = v.y - mu; d.z = v.z - mu; d.w = v.w - mu;
    float s2 = (d.x * d.x + d.y * d.y) + (d.z * d.z + d.w * d.w);
    #pragma unroll
    for (int o = 1; o < 64; o <<= 1) s2 += __shfl_xor(s2, o);
    const float rs = rsqrtf(s2 * (1.f / 256.f) + 1e-5f);

    float4 gv = *(const float4*)&gam[lane * 4];
    float4 bv = *(const float4*)&bet[lane * 4];
    float4 y;
    y.x = d.x * rs * gv.x + bv.x;
    y.y = d.y * rs * gv.y + bv.y;
    y.z = d.z * rs * gv.z + bv.z;
    y.w = d.w * rs * gv.w + bv.w;
    *(float4*)&Y[off] = y;
}

// ---------------------------------------------------------------------------
extern "C" void kernel_launch(void* const* d_in, const int* in_sizes, int n_in,
                              void* d_out, int out_size, void* d_ws, size_t ws_size,
                              hipStream_t stream)
{
    const float* x    = (const float*)d_in[0];
    const float* pos  = (const float*)d_in[1];
    const int*   mask = (const int*)d_in[2];
    const float* Wqkv = (const float*)d_in[3];
    const float* bqkv = (const float*)d_in[4];
    const float* Wpos = (const float*)d_in[5];
    const float* bpos = (const float*)d_in[6];
    const float* ln1g = (const float*)d_in[7];
    const float* ln1b = (const float*)d_in[8];
    const float* W1   = (const float*)d_in[9];
    const float* b1   = (const float*)d_in[10];
    const float* W2   = (const float*)d_in[11];
    const float* b2   = (const float*)d_in[12];
    const float* ln2g = (const float*)d_in[13];
    const float* ln2b = (const float*)d_in[14];
    float* out = (float*)d_out;

    // Workspace layout (~94 MB), regions reused by lifetime:
    //  [ 0,34M)  acat bf16 (s1-3) | accP fp32 2x16.8M (s5-6) | mid bf16 (s7-8)
    //  [34,42M)  qb (s3-5)   [42,50M) kb (s3-5)   [58,66M) vt (s3-5)
    //  [66,74M)  hb bf16 (s6-7)
    //  [74,90M)  hbuf fp32 (s6-9)
    //  [90,92M)  weights: wqk[512,768], wv[256,256], w1[1024,256], w2[256,1024]
    //  [93,94M)  lP fp32 [2][64][2048]
    //  f2 lives in d_out (written s8, LN2 in-place s9).
    char* base = (char*)d_ws;
    const size_t MB = 1024 * 1024;
    unsigned short* acat = (unsigned short*)(base + 0);
    float*          accP = (float*)(base + 0);
    unsigned short* mid  = (unsigned short*)(base + 0);
    unsigned short* qb   = (unsigned short*)(base + 34 * MB);
    unsigned short* kb   = (unsigned short*)(base + 42 * MB);
    unsigned short* vt   = (unsigned short*)(base + 58 * MB);
    unsigned short* hb   = (unsigned short*)(base + 66 * MB);
    float*          hbuf = (float*)(base + 74 * MB);
    unsigned short* wqk  = (unsigned short*)(base + 90 * MB);   // [512,768]
    unsigned short* wv   = wqk + 512 * 768;                     // [256,256]
    unsigned short* w1   = wv + 256 * 256;                      // [1024,256]
    unsigned short* w2   = w1 + 1024 * 256;                     // [256,1024]
    float*          lP   = (float*)(base + 93 * MB);            // 1 MB
    float*          f2   = out;

    dim3 blk(256);

    // s1) x,pos -> concatenated bf16 acat[M,768]
    convcat_kernel<<<dim3((3 * (int)(SZE / 8)) / 256), blk, 0, stream>>>(
        x, pos, acat, (int)(SZE / 8), (int)(2 * SZE / 8));
    // s2) all weight transposes, one launch (960 blocks)
    wtrans_all_kernel<<<dim3(960), blk, 0, stream>>>(
        Wqkv, Wpos, W1, W2, wqk, wv, w1, w2);
    // s3) merged qk + v GEMMs, one launch (768 blocks)
    qkv_kernel<<<dim3(768), blk, 0, stream>>>(
        acat, wqk, wv, bqkv, bpos, qb, kb, vt);
    // s5) split-K attention -> accP, lP  (grid 1024: 64 bh x 8 qblk x 2 kh)
    attn_kernel<<<dim3(1024), blk, 0, stream>>>(
        qb, kb, vt, mask, accP, lP);
    // s6) h = LN(x + combine(accP,lP)) -> hbuf fp32 + hb bf16
    ln1c_kernel<<<dim3(MROWS / 4), blk, 0, stream>>>(
        x, accP, lP, ln1g, ln1b, hbuf, hb);
    // s7) relu(h @ W1 + b1) -> mid bf16
    mgemm_kernel<1><<<dim3(1024 / 128, MROWS / 128), blk, 0, stream>>>(
        hb, w1, b1, nullptr, nullptr, mid, MROWS, 256, 1024, 256,
        nullptr, nullptr, nullptr);
    // s8) mid @ W2 + b2 -> f2 (= d_out)
    mgemm_kernel<0><<<dim3(256 / 128, MROWS / 128), blk, 0, stream>>>(
        mid, w2, b2, nullptr, f2, nullptr, MROWS, 1024, 256, 1024,
        nullptr, nullptr, nullptr);
    // s9) out = LN(h + ffn), in-place on d_out
    ln_kernel<<<dim3(MROWS / 4), blk, 0, stream>>>(hbuf, f2, ln2g, ln2b, out);
}

// Round 22
// 238.398 us; speedup vs baseline: 1.0199x; 1.0199x over previous
//
#include <hip/hip_runtime.h>
#include <math.h>

// Problem constants (B=8, N=2048, D=256, H=8, Dh=32)
#define BATCH 8
#define SEQ   2048
#define DIM   256
#define NHEAD 8
#define DHEAD 32
#define MROWS (BATCH*SEQ)   // 16384
#define KCAT  768           // concatenated qkv/pos K-dim

typedef short bf16x8 __attribute__((ext_vector_type(8)));
typedef float f32x4  __attribute__((ext_vector_type(4)));
typedef float f32x16 __attribute__((ext_vector_type(16)));

#define CLSCALE 0.25503485f   // log2(e)/sqrt(32): Q pre-scaled by this in mgemm

// raw hardware exp2 (single v_exp_f32; inputs are bounded log2-units,
// masked scores are -3e38 -> exp2 -> 0; no range reduction needed)
static __device__ __forceinline__ float exp2_raw(float x) {
    float r;
    asm("v_exp_f32 %0, %1" : "=v"(r) : "v"(x));
    return r;
}

// fp32 -> bf16 round-to-nearest-even (bits)
static __device__ __forceinline__ unsigned bf16rne(float f) {
    unsigned u = __float_as_uint(f);
    return (u + 0x7FFFu + ((u >> 16) & 1u)) >> 16;
}

// ---------------------------------------------------------------------------
// Fused fp32 -> bf16 convert of x and pos into concatenated acat[M,768]
// ---------------------------------------------------------------------------
__global__ __launch_bounds__(256) void convcat_kernel(
    const float* __restrict__ x, const float* __restrict__ pos,
    unsigned short* __restrict__ acat, int n1, int n2)
{
    int i = blockIdx.x * 256 + threadIdx.x;
    const float* s; size_t dst; int j;
    if (i < n1) {
        j = i; s = x;
        int row = j >> 5, c8 = (j & 31) * 8;
        dst = (size_t)row * KCAT + c8;
    } else {
        j = i - n1; if (j >= n2) return; s = pos;
        int row = j >> 6, c8 = (j & 63) * 8;
        dst = (size_t)row * KCAT + 256 + c8;
    }
    float4 a = ((const float4*)s)[2 * j];
    float4 b = ((const float4*)s)[2 * j + 1];
    union { unsigned short u[8]; uint4 v; } o;
    o.u[0] = bf16rne(a.x); o.u[1] = bf16rne(a.y);
    o.u[2] = bf16rne(a.z); o.u[3] = bf16rne(a.w);
    o.u[4] = bf16rne(b.x); o.u[5] = bf16rne(b.y);
    o.u[6] = bf16rne(b.z); o.u[7] = bf16rne(b.w);
    *(uint4*)&acat[dst] = o.v;
}

// ---------------------------------------------------------------------------
// All 5 weight transposes in ONE launch (960 blocks, blockIdx-range dispatch).
// ---------------------------------------------------------------------------
__global__ __launch_bounds__(256) void wtrans_all_kernel(
    const float* __restrict__ Wqkv, const float* __restrict__ Wpos,
    const float* __restrict__ W1, const float* __restrict__ W2,
    unsigned short* __restrict__ wqk, unsigned short* __restrict__ wv,
    unsigned short* __restrict__ w1, unsigned short* __restrict__ w2)
{
    int b = blockIdx.x;
    const float* src; unsigned short* dst;
    int srcN, srcColOff, dstK, dstKOff, nbx;
    if (b < 128)      {          src = Wqkv; dst = wqk; srcN = 768;  srcColOff = 0;   dstK = 768;  dstKOff = 0;   nbx = 16; }
    else if (b < 384) { b -= 128; src = Wpos; dst = wqk; srcN = 512;  srcColOff = 0;   dstK = 768;  dstKOff = 256; nbx = 16; }
    else if (b < 448) { b -= 384; src = Wqkv; dst = wv;  srcN = 768;  srcColOff = 512; dstK = 256;  dstKOff = 0;   nbx = 8;  }
    else if (b < 704) { b -= 448; src = W1;   dst = w1;  srcN = 1024; srcColOff = 0;   dstK = 256;  dstKOff = 0;   nbx = 32; }
    else              { b -= 704; src = W2;   dst = w2;  srcN = 256;  srcColOff = 0;   dstK = 1024; dstKOff = 0;   nbx = 8;  }
    const int tn0 = (b % nbx) * 32;
    const int tk0 = (b / nbx) * 32;

    __shared__ float tile[32][33];
    const int tx = threadIdx.x & 31;
    const int ty = threadIdx.x >> 5;
    #pragma unroll
    for (int r = ty; r < 32; r += 8)
        tile[r][tx] = src[(size_t)(tk0 + r) * srcN + srcColOff + tn0 + tx];
    __syncthreads();
    #pragma unroll
    for (int r = ty; r < 32; r += 8)
        dst[(size_t)(tn0 + r) * dstK + dstKOff + tk0 + tx] =
            (unsigned short)bf16rne(tile[tx][r]);
}

// ---------------------------------------------------------------------------
// bf16 MFMA GEMM body (device fn): C[M,Nc] = A[M,K] @ Wt[Nc,K]^T + bias.
// 128x128 tile at (bx,by), 4 waves 2x2, 4x4 frags of 16x16x32.
// Modes: 0 fp32 store | 1 relu->bf16 | 4 qk scatter | 5 v->vt transposed.
// ---------------------------------------------------------------------------
template<int MODE>
static __device__ __forceinline__ void mgemm_body(
    int bx, int by,
    const unsigned short* __restrict__ A, const unsigned short* __restrict__ Wt,
    const float* __restrict__ bias, const float* __restrict__ bias2,
    float* __restrict__ C, unsigned short* __restrict__ Cb,
    int M, int K, int Nc, int lda,
    unsigned short* __restrict__ u0, unsigned short* __restrict__ u1,
    unsigned short* __restrict__ u2)
{
    const int t    = threadIdx.x;
    const int wv   = t >> 6;
    const int lane = t & 63;
    const int g    = lane >> 4;
    const int lo   = lane & 15;
    const int wr   = wv >> 1;
    const int wc   = wv & 1;
    const int r0   = by * 128 + wr * 64;
    const int c0   = bx * 128 + wc * 64;

    f32x4 acc[4][4];
    #pragma unroll
    for (int i = 0; i < 4; ++i)
        #pragma unroll
        for (int j = 0; j < 4; ++j)
            #pragma unroll
            for (int r = 0; r < 4; ++r) acc[i][j][r] = 0.f;

    const unsigned short* aP[4];
    const unsigned short* bP[4];
    #pragma unroll
    for (int i = 0; i < 4; ++i) {
        aP[i] = A  + (size_t)(r0 + 16 * i + lo) * lda + g * 8;
        bP[i] = Wt + (size_t)(c0 + 16 * i + lo) * K + g * 8;
    }

    bf16x8 aA[4], bA[4], aB[4], bB[4];
    #pragma unroll
    for (int i = 0; i < 4; ++i) {
        aA[i] = *(const bf16x8*)(aP[i]);
        bA[i] = *(const bf16x8*)(bP[i]);
    }

    for (int k0 = 0; k0 < K; k0 += 64) {
        #pragma unroll
        for (int i = 0; i < 4; ++i) {
            aB[i] = *(const bf16x8*)(aP[i] + k0 + 32);
            bB[i] = *(const bf16x8*)(bP[i] + k0 + 32);
        }
        #pragma unroll
        for (int i = 0; i < 4; ++i)
            #pragma unroll
            for (int j = 0; j < 4; ++j)
                acc[i][j] = __builtin_amdgcn_mfma_f32_16x16x32_bf16(
                    aA[i], bA[j], acc[i][j], 0, 0, 0);
        if (k0 + 64 < K) {
            #pragma unroll
            for (int i = 0; i < 4; ++i) {
                aA[i] = *(const bf16x8*)(aP[i] + k0 + 64);
                bA[i] = *(const bf16x8*)(bP[i] + k0 + 64);
            }
        }
        #pragma unroll
        for (int i = 0; i < 4; ++i)
            #pragma unroll
            for (int j = 0; j < 4; ++j)
                acc[i][j] = __builtin_amdgcn_mfma_f32_16x16x32_bf16(
                    aB[i], bB[j], acc[i][j], 0, 0, 0);
    }

    #pragma unroll
    for (int j = 0; j < 4; ++j) {
        const int col = c0 + 16 * j + lo;
        const float bs = bias[col] + ((MODE == 4) ? bias2[col] : 0.f);
        #pragma unroll
        for (int i = 0; i < 4; ++i) {
            if (MODE == 5) {
                const int row0 = r0 + 16 * i + g * 4;
                const int bb   = row0 >> 11;
                const int nn0  = row0 & (SEQ - 1);
                const int hh   = col >> 5;
                const int dh   = col & 31;
                uint2 pk;
                pk.x = bf16rne(acc[i][j][0] + bs) | (bf16rne(acc[i][j][1] + bs) << 16);
                pk.y = bf16rne(acc[i][j][2] + bs) | (bf16rne(acc[i][j][3] + bs) << 16);
                *(uint2*)&u2[(((size_t)bb * NHEAD + hh) * DHEAD + dh) * SEQ + nn0] = pk;
            } else {
                #pragma unroll
                for (int r = 0; r < 4; ++r) {
                    const int row = r0 + 16 * i + g * 4 + r;
                    float v = acc[i][j][r] + bs;
                    if (MODE == 0) {
                        C[(size_t)row * Nc + col] = v;
                    } else if (MODE == 1) {
                        Cb[(size_t)row * Nc + col] =
                            (unsigned short)bf16rne(fmaxf(v, 0.f));
                    } else {   // MODE 4
                        const int bb = row >> 11;
                        const int nn = row & (SEQ - 1);
                        const int which = col >> 8;
                        const int d  = col & 255;
                        const int hh = d >> 5;
                        const int dh = d & 31;
                        const size_t dst =
                            (((size_t)bb * NHEAD + hh) * SEQ + nn) * DHEAD + dh;
                        if (which == 0) {
                            u0[dst] = (unsigned short)bf16rne(v * CLSCALE);
                        } else {
                            u1[dst] = (unsigned short)bf16rne(v);
                        }
                    }
                }
            }
        }
    }
}

template<int MODE>
__global__ __launch_bounds__(256, 3) void mgemm_kernel(
    const unsigned short* __restrict__ A, const unsigned short* __restrict__ Wt,
    const float* __restrict__ bias, const float* __restrict__ bias2,
    float* __restrict__ C, unsigned short* __restrict__ Cb,
    int M, int K, int Nc, int lda,
    unsigned short* __restrict__ u0, unsigned short* __restrict__ u1,
    unsigned short* __restrict__ u2)
{
    mgemm_body<MODE>(blockIdx.x, blockIdx.y, A, Wt, bias, bias2, C, Cb,
                     M, K, Nc, lda, u0, u1, u2);
}

// merged qkv kernel: blocks [0,512) = qk GEMM; [512,768) = v GEMM.
__global__ __launch_bounds__(256, 3) void qkv_kernel(
    const unsigned short* __restrict__ acat,
    const unsigned short* __restrict__ wqk, const unsigned short* __restrict__ wv,
    const float* __restrict__ bqkv, const float* __restrict__ bpos,
    unsigned short* __restrict__ qb, unsigned short* __restrict__ kb,
    unsigned short* __restrict__ vt)
{
    const int b = blockIdx.x;
    if (b < 512) {
        mgemm_body<4>(b & 3, b >> 2, acat, wqk, bqkv, bpos, nullptr, nullptr,
                      MROWS, KCAT, 512, KCAT, qb, kb, nullptr);
    } else {
        const int b2 = b - 512;
        mgemm_body<5>(b2 & 1, b2 >> 1, acat, wv, bqkv + 512, nullptr,
                      nullptr, nullptr, MROWS, 256, 256, KCAT,
                      nullptr, nullptr, vt);
    }
}

// ---------------------------------------------------------------------------
// MFMA flash attention, 32x32 fragments. Wave = 2 q-tiles of 32 (64 q rows),
// block = 4 waves = 256 q rows, grid 512 = 64 bh x 8 qblk (XCD-swizzled).
// Swapped QK^T at 32x32: S^T = K·Q^T, C-layout col=lane&31=q,
// row=key=(r&3)+8(r>>2)+4h (h=lane>>5). Each lane holds a full 16-key
// P-slice for ONE q -> PV B-frags rebuilt with 4 v_permlane32_swap per
// tile (replaces 16 ds_bpermute of the 16x16 version; DS pipe ~idle).
// Static-max softmax (Q pre-scaled; bias -3e38 -> p=0). PV: O^T = V^T·P^T,
// acc col=q -> lane-local 1/l scaling, regs 4c..4c+3 = 4 consecutive d ->
// direct float4 stores (no LDS transpose).
// permlane32_swap(a,b): a' = [a_lo, b_lo], b' = [a_hi, b_hi] — so
// swap(w00,w10) yields (fragA word0, fragA word2) for all lanes.
// ---------------------------------------------------------------------------
__global__ __launch_bounds__(256) void attn_kernel(
    const unsigned short* __restrict__ Qb, const unsigned short* __restrict__ Kb,
    const unsigned short* __restrict__ Vt, const int* __restrict__ mask,
    float* __restrict__ O)
{
    __shared__ float bias_s[SEQ];        // 8 KB mask bias (0 / -3e38)

    const int t    = threadIdx.x;
    const int wv   = t >> 6;
    const int lane = t & 63;
    const int h    = lane >> 5;          // lane half
    const int ql   = lane & 31;          // q-in-tile / K-row / V-d row

    const int sb   = ((blockIdx.x & 7) << 6) | (blockIdx.x >> 3);  // XCD swizzle
    const int bh   = sb >> 3;            // 0..63
    const int qblk = sb & 7;             // 0..7
    const int bb   = bh >> 3;
    const int hh   = bh & 7;
    const int qt   = qblk * 256 + wv * 64;   // wave owns q rows qt..qt+63

    const int* mrow = mask + bb * SEQ;
    for (int i = t; i < SEQ; i += 256)
        bias_s[i] = mrow[i] ? -3.0e38f : 0.0f;
    __syncthreads();

    const unsigned short* Qh = Qb + (size_t)bh * SEQ * 32;
    const unsigned short* Kh = Kb + (size_t)bh * SEQ * 32;
    const unsigned short* Vh = Vt + (size_t)bh * 32 * SEQ;

    // Q B-frags: qf[tile][d-half]: Q[qt+32*tile+ql][16*dh + 8*h .. +7]
    bf16x8 qf[2][2];
    #pragma unroll
    for (int i = 0; i < 2; ++i)
        #pragma unroll
        for (int dh = 0; dh < 2; ++dh)
            qf[i][dh] = *(const bf16x8*)&Qh[(size_t)(qt + 32 * i + ql) * 32 + 16 * dh + 8 * h];

    f32x16 acc[2];                       // O^T per tile: col=q, row=d
    #pragma unroll
    for (int i = 0; i < 2; ++i)
        #pragma unroll
        for (int r = 0; r < 16; ++r) acc[i][r] = 0.f;
    float l[2] = {0.f, 0.f};

    for (int k0 = 0; k0 < SEQ; k0 += 32) {
        // K A-frags (d-halves), V^T A-frags (key-halves)
        bf16x8 kf0 = *(const bf16x8*)&Kh[(size_t)(k0 + ql) * 32 + 8 * h];
        bf16x8 kf1 = *(const bf16x8*)&Kh[(size_t)(k0 + ql) * 32 + 16 + 8 * h];
        bf16x8 vf0 = *(const bf16x8*)&Vh[(size_t)ql * SEQ + k0 + 8 * h];
        bf16x8 vf1 = *(const bf16x8*)&Vh[(size_t)ql * SEQ + k0 + 16 + 8 * h];

        // bias C-in: reg r = bias_s[k0 + (r&3) + 8*(r>>2) + 4*h]
        f32x16 cbv;
        #pragma unroll
        for (int c = 0; c < 4; ++c) {
            f32x4 cb = *(const f32x4*)&bias_s[k0 + 4 * h + 8 * c];
            #pragma unroll
            for (int e = 0; e < 4; ++e) cbv[4 * c + e] = cb[e];
        }

        #pragma unroll
        for (int i = 0; i < 2; ++i) {
            // ---- QK^T: 2 chained MFMAs over d=32 ----
            __builtin_amdgcn_s_setprio(1);
            f32x16 s = __builtin_amdgcn_mfma_f32_32x32x16_bf16(
                kf0, qf[i][0], cbv, 0, 0, 0);
            s = __builtin_amdgcn_mfma_f32_32x32x16_bf16(
                kf1, qf[i][1], s, 0, 0, 0);
            __builtin_amdgcn_s_setprio(0);

            // ---- p = exp2(s); all 16 regs are q = ql ----
            float p[16];
            float tl = 0.f;
            #pragma unroll
            for (int r = 0; r < 16; ++r) {
                p[r] = exp2_raw(s[r]);
                tl += p[r];
            }
            l[i] += tl;

            // ---- pack pairs, rebuild PV B-frags via permlane32_swap ----
            unsigned w00, w01, w10, w11, w20, w21, w30, w31;
            asm("v_cvt_pk_bf16_f32 %0, %1, %2" : "=v"(w00) : "v"(p[0]),  "v"(p[1]));
            asm("v_cvt_pk_bf16_f32 %0, %1, %2" : "=v"(w01) : "v"(p[2]),  "v"(p[3]));
            asm("v_cvt_pk_bf16_f32 %0, %1, %2" : "=v"(w10) : "v"(p[4]),  "v"(p[5]));
            asm("v_cvt_pk_bf16_f32 %0, %1, %2" : "=v"(w11) : "v"(p[6]),  "v"(p[7]));
            asm("v_cvt_pk_bf16_f32 %0, %1, %2" : "=v"(w20) : "v"(p[8]),  "v"(p[9]));
            asm("v_cvt_pk_bf16_f32 %0, %1, %2" : "=v"(w21) : "v"(p[10]), "v"(p[11]));
            asm("v_cvt_pk_bf16_f32 %0, %1, %2" : "=v"(w30) : "v"(p[12]), "v"(p[13]));
            asm("v_cvt_pk_bf16_f32 %0, %1, %2" : "=v"(w31) : "v"(p[14]), "v"(p[15]));
            // swap(a,b): a'=[a_lo,b_lo], b'=[a_hi,b_hi]
            asm volatile("v_permlane32_swap_b32 %0, %1" : "+v"(w00), "+v"(w10));
            asm volatile("v_permlane32_swap_b32 %0, %1" : "+v"(w01), "+v"(w11));
            asm volatile("v_permlane32_swap_b32 %0, %1" : "+v"(w20), "+v"(w30));
            asm volatile("v_permlane32_swap_b32 %0, %1" : "+v"(w21), "+v"(w31));
            union { unsigned u[4]; bf16x8 v; } pa, pb;
            pa.u[0] = w00; pa.u[1] = w01; pa.u[2] = w10; pa.u[3] = w11;
            pb.u[0] = w20; pb.u[1] = w21; pb.u[2] = w30; pb.u[3] = w31;

            // ---- PV: O^T += V^T · P^T (2 MFMAs over 32 keys) ----
            __builtin_amdgcn_s_setprio(1);
            acc[i] = __builtin_amdgcn_mfma_f32_32x32x16_bf16(
                vf0, pa.v, acc[i], 0, 0, 0);
            acc[i] = __builtin_amdgcn_mfma_f32_32x32x16_bf16(
                vf1, pb.v, acc[i], 0, 0, 0);
            __builtin_amdgcn_s_setprio(0);
        }
    }

    // epilogue: finish l (cross-half), scale, direct float4 stores
    #pragma unroll
    for (int i = 0; i < 2; ++i) {
        l[i] += __shfl_xor(l[i], 32);
        const float inv = (l[i] > 0.f) ? 1.0f / l[i] : 0.f;
        const size_t rowoff = (size_t)(bb * SEQ + qt + 32 * i + ql) * DIM + hh * 32;
        #pragma unroll
        for (int c = 0; c < 4; ++c) {
            float4 ov;
            ov.x = acc[i][4 * c + 0] * inv;
            ov.y = acc[i][4 * c + 1] * inv;
            ov.z = acc[i][4 * c + 2] * inv;
            ov.w = acc[i][4 * c + 3] * inv;
            *(float4*)&O[rowoff + 4 * h + 8 * c] = ov;
        }
    }
}

// ---------------------------------------------------------------------------
// Fused residual + LayerNorm: 1 wave = 1 row, shfl-only. Optional bf16 out.
// ---------------------------------------------------------------------------
__global__ __launch_bounds__(256) void ln_kernel(
    const float* __restrict__ X, const float* __restrict__ R,
    const float* __restrict__ gam, const float* __restrict__ bet,
    float* __restrict__ Y, unsigned short* __restrict__ Yb)
{
    const int lane = threadIdx.x & 63;
    const int row  = blockIdx.x * 4 + (threadIdx.x >> 6);
    const size_t off = (size_t)row * DIM + lane * 4;

    float4 xv = *(const float4*)&X[off];
    float4 rv = *(const float4*)&R[off];
    float4 v;
    v.x = xv.x + rv.x; v.y = xv.y + rv.y;
    v.z = xv.z + rv.z; v.w = xv.w + rv.w;

    float s = (v.x + v.y) + (v.z + v.w);
    #pragma unroll
    for (int o = 1; o < 64; o <<= 1) s += __shfl_xor(s, o);
    const float mu = s * (1.f / 256.f);

    float4 d;
    d.x = v.x - mu; d.y = v.y - mu; d.z = v.z - mu; d.w = v.w - mu;
    float s2 = (d.x * d.x + d.y * d.y) + (d.z * d.z + d.w * d.w);
    #pragma unroll
    for (int o = 1; o < 64; o <<= 1) s2 += __shfl_xor(s2, o);
    const float rs = rsqrtf(s2 * (1.f / 256.f) + 1e-5f);

    float4 gv = *(const float4*)&gam[lane * 4];
    float4 bv = *(const float4*)&bet[lane * 4];
    float4 y;
    y.x = d.x * rs * gv.x + bv.x;
    y.y = d.y * rs * gv.y + bv.y;
    y.z = d.z * rs * gv.z + bv.z;
    y.w = d.w * rs * gv.w + bv.w;
    *(float4*)&Y[off] = y;

    if (Yb) {
        uint2 pk;
        pk.x = bf16rne(y.x) | (bf16rne(y.y) << 16);
        pk.y = bf16rne(y.z) | (bf16rne(y.w) << 16);
        *(uint2*)&Yb[off] = pk;
    }
}

// ---------------------------------------------------------------------------
extern "C" void kernel_launch(void* const* d_in, const int* in_sizes, int n_in,
                              void* d_out, int out_size, void* d_ws, size_t ws_size,
                              hipStream_t stream)
{
    const float* x    = (const float*)d_in[0];
    const float* pos  = (const float*)d_in[1];
    const int*   mask = (const int*)d_in[2];
    const float* Wqkv = (const float*)d_in[3];
    const float* bqkv = (const float*)d_in[4];
    const float* Wpos = (const float*)d_in[5];
    const float* bpos = (const float*)d_in[6];
    const float* ln1g = (const float*)d_in[7];
    const float* ln1b = (const float*)d_in[8];
    const float* W1   = (const float*)d_in[9];
    const float* b1   = (const float*)d_in[10];
    const float* W2   = (const float*)d_in[11];
    const float* b2   = (const float*)d_in[12];
    const float* ln2g = (const float*)d_in[13];
    const float* ln2b = (const float*)d_in[14];
    float* out = (float*)d_out;

    // Workspace layout (~92 MB), regions reused by lifetime (round-20 map)
    char* base = (char*)d_ws;
    const size_t MB = 1024 * 1024;
    const size_t SZ = (size_t)MROWS * DIM;           // 4,194,304 elements
    unsigned short* acat = (unsigned short*)(base + 0);
    float*          ao   = (float*)(base + 0);
    unsigned short* mid  = (unsigned short*)(base + 0);
    unsigned short* qb   = (unsigned short*)(base + 34 * MB);
    unsigned short* kb   = (unsigned short*)(base + 42 * MB);
    unsigned short* vt   = (unsigned short*)(base + 58 * MB);
    unsigned short* hb   = (unsigned short*)(base + 66 * MB);
    float*          hbuf = (float*)(base + 74 * MB);
    unsigned short* wqk  = (unsigned short*)(base + 90 * MB);   // [512,768]
    unsigned short* wv   = wqk + 512 * 768;                     // [256,256]
    unsigned short* w1   = wv + 256 * 256;                      // [1024,256]
    unsigned short* w2   = w1 + 1024 * 256;                     // [256,1024]
    float*          f2   = out;

    dim3 blk(256);

    // s1) x,pos -> concatenated bf16 acat[M,768]
    convcat_kernel<<<dim3((3 * (int)(SZ / 8)) / 256), blk, 0, stream>>>(
        x, pos, acat, (int)(SZ / 8), (int)(2 * SZ / 8));
    // s2) all weight transposes, one launch (960 blocks)
    wtrans_all_kernel<<<dim3(960), blk, 0, stream>>>(
        Wqkv, Wpos, W1, W2, wqk, wv, w1, w2);
    // s3) merged qk + v GEMMs, one launch (768 blocks)
    qkv_kernel<<<dim3(768), blk, 0, stream>>>(
        acat, wqk, wv, bqkv, bpos, qb, kb, vt);
    // s5) attention (32x32 frags) -> ao  (grid 512)
    attn_kernel<<<dim3(BATCH * NHEAD * (SEQ / 256)), blk, 0, stream>>>(
        qb, kb, vt, mask, ao);
    // s6) h = LN(x + ao) -> hbuf fp32 + hb bf16
    ln_kernel<<<dim3(MROWS / 4), blk, 0, stream>>>(x, ao, ln1g, ln1b, hbuf, hb);
    // s7) relu(h @ W1 + b1) -> mid bf16
    mgemm_kernel<1><<<dim3(1024 / 128, MROWS / 128), blk, 0, stream>>>(
        hb, w1, b1, nullptr, nullptr, mid, MROWS, 256, 1024, 256,
        nullptr, nullptr, nullptr);
    // s8) mid @ W2 + b2 -> f2 (= d_out)
    mgemm_kernel<0><<<dim3(256 / 128, MROWS / 128), blk, 0, stream>>>(
        mid, w2, b2, nullptr, f2, nullptr, MROWS, 1024, 256, 1024,
        nullptr, nullptr, nullptr);
    // s9) out = LN(h + ffn), in-place on d_out
    ln_kernel<<<dim3(MROWS / 4), blk, 0, stream>>>(hbuf, f2, ln2g, ln2b, out, nullptr);
}